// Round 9
// baseline (109.683 us; speedup 1.0000x reference)
//
#include <hip/hip_runtime.h>
#include <hip/hip_bf16.h>
#include <stdint.h>
#include <math.h>

#define Bq 4
#define Cc 256
#define Nn 4096
#define CQ 64
// 0.25 (=C^-0.25 per side) * sqrt(log2 e), folded into w_qk cast
#define QKSCALE 0.30028060219661246f

typedef short s16x4 __attribute__((ext_vector_type(4)));
typedef short s16x8 __attribute__((ext_vector_type(8)));
typedef unsigned int u32x4 __attribute__((ext_vector_type(4)));
typedef float f32x16 __attribute__((ext_vector_type(16)));

#define MFMA32(a,b,c) __builtin_amdgcn_mfma_f32_32x32x16_bf16((a),(b),(c),0,0,0)

static __device__ __forceinline__ unsigned short f2b(float f) {
  unsigned int u = __float_as_uint(f);
  u += 0x7FFFu + ((u >> 16) & 1u);   // RNE
  return (unsigned short)(u >> 16);
}

static __device__ __forceinline__ unsigned short f2bh(float f) {
  __hip_bfloat16 h = __float2bfloat16(f);
  return __builtin_bit_cast(unsigned short, h);
}

static __device__ __forceinline__ float b2f(unsigned short u) {
  return __uint_as_float(((unsigned int)u) << 16);
}

static __device__ __forceinline__ float fexp2(float x) {
#if __has_builtin(__builtin_amdgcn_exp2f)
  return __builtin_amdgcn_exp2f(x);
#else
  return exp2f(x);
#endif
}

static __device__ __forceinline__ f32x16 fz16() {
  f32x16 z;
#pragma unroll
  for (int i = 0; i < 16; i++) z[i] = 0.0f;
  return z;
}

static __device__ __forceinline__ float sum16(f32x16 E) {
  return (((E[0] + E[1]) + (E[2] + E[3])) + ((E[4] + E[5]) + (E[6] + E[7]))) +
         (((E[8] + E[9]) + (E[10] + E[11])) + ((E[12] + E[13]) + (E[14] + E[15])));
}

// ---------------- K0: weight cast + BN precompute ---------------------------
// R25 post-mortem note (R24): inlining this into k_proj/k_attn multiplied the
// once-per-launch weight cast by grid size (160MB+64MB L2 reads) — keep it.
__global__ __launch_bounds__(256) void k_prep(
    const float* __restrict__ wqk, const float* __restrict__ wv,
    const float* __restrict__ wlbr, const float* __restrict__ blbr,
    const float* __restrict__ gamma, const float* __restrict__ beta,
    const float* __restrict__ mean, const float* __restrict__ var,
    unsigned short* __restrict__ Wcat, float* __restrict__ sd) {
  int bx = blockIdx.x, t = threadIdx.x;
  if (bx < 576) {
    float v;
    if (bx < 64) v = wqk[bx * 256 + t] * QKSCALE;
    else if (bx < 320) v = wv[(bx - 64) * 256 + t];
    else v = wlbr[(bx - 320) * 256 + t];
    Wcat[bx * 256 + t] = f2b(v);
  } else {
    float s = gamma[t] * rsqrtf(var[t] + 1e-5f);
    sd[t] = s;
    sd[256 + t] = beta[t] + (blbr[t] - mean[t]) * s;
  }
}

// ---------------- K1: fused transpose + projections + qk row-norms ----------
// V written fragment-major Vf[b][ntile32][kk][g][c][j] (R15-verified).
__global__ __launch_bounds__(640) void k_proj(const float* __restrict__ x,
                                              const unsigned short* __restrict__ Wcat,
                                              const float* __restrict__ bv,
                                              unsigned short* __restrict__ qkT,
                                              unsigned short* __restrict__ Vf,
                                              float* __restrict__ nrm) {
  __shared__ unsigned short xs[32 * 264];  // [32 n][256 c], stride 264
  __shared__ float npart[64];              // [2 qwave][32 n] norm partials
  int bx = blockIdx.x;
  int b = bx >> 7;
  int ntile = bx & 127;
  int n0 = ntile * 32;
  int t = threadIdx.x;
  const float* xb = x + (size_t)b * Cc * Nn;
  // stage: transpose + cast. chunk u: c = u>>2, j = (u&3)*8 (8 n-floats)
  for (int u = t; u < 1024; u += 640) {
    int c = u >> 2, j = (u & 3) * 8;
    const float* src = &xb[(size_t)c * Nn + n0 + j];
    float4 v0 = *(const float4*)src;
    float4 v1 = *(const float4*)(src + 4);
    xs[(j + 0) * 264 + c] = f2b(v0.x);
    xs[(j + 1) * 264 + c] = f2b(v0.y);
    xs[(j + 2) * 264 + c] = f2b(v0.z);
    xs[(j + 3) * 264 + c] = f2b(v0.w);
    xs[(j + 4) * 264 + c] = f2b(v1.x);
    xs[(j + 5) * 264 + c] = f2b(v1.y);
    xs[(j + 6) * 264 + c] = f2b(v1.z);
    xs[(j + 7) * 264 + c] = f2b(v1.w);
  }
  int w = t >> 6, a = t & 31, g = (t >> 5) & 1;
  bool isqk = (w >= 8);
  int row0 = isqk ? (w - 8) * 32 : 64 + w * 32;  // Wcat row base
  s16x8 wf[16];
#pragma unroll
  for (int kc = 0; kc < 16; kc++)
    wf[kc] = *(const s16x8*)&Wcat[(size_t)(row0 + a) * 256 + kc * 16 + 8 * g];
  __syncthreads();
  f32x16 acc = fz16();
#pragma unroll
  for (int kc = 0; kc < 16; kc++) {
    s16x8 xf = *(const s16x8*)&xs[a * 264 + kc * 16 + 8 * g];
    acc = MFMA32(xf, wf[kc], acc);  // D[n][row0-row] (operand-swap, both paths)
  }
  if (isqk) {
    unsigned short* dst = qkT + ((size_t)b * Nn + n0) * CQ;
    int q0 = row0;
#pragma unroll
    for (int r = 0; r < 16; r++) {
      int n = (r & 3) + 8 * (r >> 2) + 4 * g;
      dst[(size_t)n * CQ + q0 + a] = f2b(acc[r]);
    }
    // row-norm partials: sum_q acc[r]^2 over this wave's 32 q (lanes)
    float s2[16];
#pragma unroll
    for (int r = 0; r < 16; r++) {
      float v = acc[r] * acc[r];
#pragma unroll
      for (int off = 1; off < 32; off <<= 1) v += __shfl_xor(v, off, 64);
      s2[r] = v;
    }
    if ((t & 31) == 0) {  // lanes 0 (g=0) and 32 (g=1) write their 16 n's
#pragma unroll
      for (int r = 0; r < 16; r++) {
        int n = (r & 3) + 8 * (r >> 2) + 4 * g;
        npart[(w - 8) * 32 + n] = s2[r];
      }
    }
  } else {
    int c0 = row0 - 64;
    float bvv = bv[c0 + a];
    // acc[r] = V[n_local = sigma0(r&7) + 16*(r>>3) + 4g][c0+a]
    s16x8 vlo, vhi;
#pragma unroll
    for (int r = 0; r < 8; r++) {
      vlo[r] = (short)f2b(acc[r] + bvv);
      vhi[r] = (short)f2b(acc[8 + r] + bvv);
    }
    // Vf[b][ntile][kk][g][c][j]: strides (shorts) j:1, c:8, g:2048, kk:4096, ntile:8192
    unsigned short* dstF =
        Vf + ((size_t)(b * 128 + ntile) * 4 + g) * 2048 + (size_t)(c0 + a) * 8;
    *(s16x8*)dstF = vlo;             // kk=0
    *(s16x8*)(dstF + 4096) = vhi;    // kk=1
  }
  __syncthreads();  // npart ready
  if (t < 32) nrm[(size_t)b * Nn + n0 + t] = sqrtf(npart[t] + npart[32 + t]);
}

// ---------------- K2: flash attention (R17 loop) + fused LBR epilogue -------
// R25 = R23 verbatim + T5 s_setprio around the MFMA clusters. Mechanism match:
// m191 (attn, independent waves) +4-7%; m190 (GEMM lockstep) null. Our 8
// waves are barrier-free independent streams -> setprio lets an MFMA-entering
// wave preempt its SIMD-sibling's VALU/load issue (breaks contention phase-
// lock at runtime, where R20's compile-time SGB pinning failed). Bit-identical.
__global__ __launch_bounds__(512, 2) void k_attn(const unsigned short* __restrict__ qkT,
                                                 const unsigned short* __restrict__ Vf,
                                                 const float* __restrict__ nrm,
                                                 const unsigned short* __restrict__ Wcat,
                                                 const float* __restrict__ sd,
                                                 const float* __restrict__ x,
                                                 float* __restrict__ out) {
  __shared__ __align__(16) float Pf[4 * 128 * 33];   // [ns][c_local 128][m 32+pad]
  __shared__ float Ls[4 * 64];                       // [ns][m-local 0..63]
  __shared__ unsigned short xs2[64 * 266];           // xr tile [64 n][256 c]+pad
  __shared__ float sdL[512];                         // BN scale/shift
  __shared__ float wmx[8];
  int bx = blockIdx.x;
  int id = ((bx & 7) << 5) | (bx >> 3);  // XCD swizzle, 256 = 8 x 32, bijective
  int b = id >> 6;
  int m0 = (id & 63) * 64;
  int t = threadIdx.x;
  int w = t >> 6, a = t & 31, g = (t >> 5) & 1;
  int cs = w >> 2, ns = w & 3;  // same-SIMD waves share ns -> Q frags L1-hot
  const unsigned short* qkTb = qkT + (size_t)b * Nn * CQ;
  sdL[t < 512 ? t : 0] = sd[t < 512 ? t : 0];
  // block-local batch max of nrm
  const float* nrmb = nrm + (size_t)b * Nn;
  float lm = 0.0f;
#pragma unroll
  for (int i = 0; i < 8; i++) lm = fmaxf(lm, nrmb[t + i * 512]);
#pragma unroll
  for (int off = 1; off < 64; off <<= 1) lm = fmaxf(lm, __shfl_xor(lm, off, 64));
  if ((t & 63) == 0) wmx[w] = lm;
  __syncthreads();
  float mxf = fmaxf(fmaxf(fmaxf(wmx[0], wmx[1]), fmaxf(wmx[2], wmx[3])),
                    fmaxf(fmaxf(wmx[4], wmx[5]), fmaxf(wmx[6], wmx[7])));
  // B operands: columns m0..m0+31 (mt=0) and m0+32..m0+63 (mt=1)
  s16x8 Bq0[4], Bq1[4];
#pragma unroll
  for (int kc = 0; kc < 4; kc++) {
    Bq0[kc] = *(const s16x8*)&qkTb[(size_t)(m0 + a) * CQ + kc * 16 + 8 * g];
    Bq1[kc] = *(const s16x8*)&qkTb[(size_t)(m0 + 32 + a) * CQ + kc * 16 + 8 * g];
  }
  // Cauchy-Schwarz column bound: Mh >= max_n E[n,mcol]
  float Mh0 = nrmb[m0 + a] * mxf + 0.01f;
  float Mh1 = nrmb[m0 + 32 + a] * mxf + 0.01f;
  // V fragment base for this lane: Vf[b][nt][kk][g][c][j], c = cs*128 + ct*32 + a
  const unsigned short* Vc = Vf + (size_t)b * 1048576 + (size_t)g * 2048 +
                             (size_t)(cs * 128 + a) * 8;
  f32x16 acc[8];  // [mt*4+ct]: O^T partial, m = m0+mt*32+row, c = cs*128+ct*32+a
#pragma unroll
  for (int i = 0; i < 8; i++) acc[i] = fz16();
  float Lp0 = 0.0f, Lp1 = 0.0f;
  s16x8 qf[4];  // A operand: Q rows nt*32 + a (prefetched one tile ahead)
#pragma unroll
  for (int kc = 0; kc < 4; kc++)
    qf[kc] = *(const s16x8*)&qkTb[(size_t)(ns * 32 + a) * CQ + kc * 16 + 8 * g];
#pragma unroll 1
  for (int nt = ns; nt < 128; nt += 4) {
    const unsigned short* Vt = Vc + (size_t)nt * 8192;
    f32x16 E0 = fz16(), E1 = fz16();
    __builtin_amdgcn_s_setprio(1);  // QK MFMA cluster
#pragma unroll
    for (int kc = 0; kc < 4; kc++) E0 = MFMA32(qf[kc], Bq0[kc], E0);
    s16x8 va0, va1, va2, va3;  // (ct0,kk0) (ct0,kk1) (ct1,kk0) (ct1,kk1)
    va0 = *(const s16x8*)&Vt[0];
    va1 = *(const s16x8*)&Vt[4096];
    va2 = *(const s16x8*)&Vt[256];
    va3 = *(const s16x8*)&Vt[4096 + 256];
#pragma unroll
    for (int kc = 0; kc < 4; kc++) E1 = MFMA32(qf[kc], Bq1[kc], E1);
    __builtin_amdgcn_s_setprio(0);
    int ntn = (nt + 4) & 127;  // wrap on last iter: harmless dummy reload
#pragma unroll
    for (int kc = 0; kc < 4; kc++)
      qf[kc] = *(const s16x8*)&qkTb[(size_t)(ntn * 32 + a) * CQ + kc * 16 + 8 * g];
    // softmax mt=0 (E dies into packed P -> keeps transient VGPR low)
#pragma unroll
    for (int r = 0; r < 16; r++) E0[r] = fexp2(E0[r] - Mh0);
    Lp0 += sum16(E0);
    s16x8 p00, p01;
#pragma unroll
    for (int j = 0; j < 8; j++) {
      p00[j] = (short)f2bh(E0[j]);
      p01[j] = (short)f2bh(E0[8 + j]);
    }
    // softmax mt=1
#pragma unroll
    for (int r = 0; r < 16; r++) E1[r] = fexp2(E1[r] - Mh1);
    Lp1 += sum16(E1);
    s16x8 p10, p11;
#pragma unroll
    for (int j = 0; j < 8; j++) {
      p10[j] = (short)f2bh(E1[j]);
      p11[j] = (short)f2bh(E1[8 + j]);
    }
    // PV ct0/ct1: kk0 round then kk1 round (8 independent acc chains)
    __builtin_amdgcn_s_setprio(1);  // PV MFMA cluster
    acc[0] = MFMA32(p00, va0, acc[0]);
    acc[4] = MFMA32(p10, va0, acc[4]);
    acc[1] = MFMA32(p00, va2, acc[1]);
    acc[5] = MFMA32(p10, va2, acc[5]);
    acc[0] = MFMA32(p01, va1, acc[0]);
    acc[4] = MFMA32(p11, va1, acc[4]);
    acc[1] = MFMA32(p01, va3, acc[1]);
    acc[5] = MFMA32(p11, va3, acc[5]);
    s16x8 vb0, vb1, vb2, vb3;  // ct2, ct3
    vb0 = *(const s16x8*)&Vt[512];
    vb1 = *(const s16x8*)&Vt[4096 + 512];
    vb2 = *(const s16x8*)&Vt[768];
    vb3 = *(const s16x8*)&Vt[4096 + 768];
    acc[2] = MFMA32(p00, vb0, acc[2]);
    acc[6] = MFMA32(p10, vb0, acc[6]);
    acc[3] = MFMA32(p00, vb2, acc[3]);
    acc[7] = MFMA32(p10, vb2, acc[7]);
    acc[2] = MFMA32(p01, vb1, acc[2]);
    acc[6] = MFMA32(p11, vb1, acc[6]);
    acc[3] = MFMA32(p01, vb3, acc[3]);
    acc[7] = MFMA32(p11, vb3, acc[7]);
    __builtin_amdgcn_s_setprio(0);
  }
  // ---- epilogue A: combine ns-partials per (mt,cs) quadrant -> xr in LDS ----
  float Lw0 = Lp0 + __shfl_xor(Lp0, 32, 64);  // sum both g-halves (n rows)
  float Lw1 = Lp1 + __shfl_xor(Lp1, 32, 64);
  if (cs == 0 && (t & 63) < 32) {  // cs=1 partials are identical; write once
    Ls[ns * 64 + a] = Lw0;
    Ls[ns * 64 + 32 + a] = Lw1;
  }
  const float* xb = x + (size_t)b * Cc * Nn;
  float* ob = out + (size_t)b * Cc * Nn;
#pragma unroll
  for (int q = 0; q < 4; q++) {
    int qmt = q >> 1, qcs = q & 1;
    int m = t & 31, c8 = t >> 5;  // c8 in 0..15
    // x loads for this quadrant issued BEFORE the syncs: latency hidden
    float xq[8];
#pragma unroll
    for (int j = 0; j < 8; j++)
      xq[j] = xb[(size_t)(qcs * 128 + c8 * 8 + j) * Nn + m0 + qmt * 32 + m];
    __syncthreads();  // also guards Ls on q=0; prior reads done before rewrite
    if (cs == qcs) {
#pragma unroll
      for (int ct = 0; ct < 4; ct++) {
        float* dst = &Pf[(size_t)(ns * 128 + ct * 32 + a) * 33];
        f32x16 A = acc[qmt * 4 + ct];
#pragma unroll
        for (int r = 0; r < 16; r++) {
          int mrow = (r & 3) + 8 * (r >> 2) + 4 * g;
          dst[mrow] = A[r];  // bank = (a + 4g) mod 32 -> 2-way, free
        }
      }
    }
    __syncthreads();
    // combine: 512 threads x 8 outputs; rows m0+qmt*32+m, cols qcs*128+..
    float rL = 1.0f / (((Ls[qmt * 32 + m] + Ls[64 + qmt * 32 + m]) +
                        (Ls[128 + qmt * 32 + m] + Ls[192 + qmt * 32 + m])));
    s16x8 xv;
#pragma unroll
    for (int j = 0; j < 8; j++) {
      int cl = qcs * 128 + c8 * 8 + j;
      float s = ((Pf[(0 * 128 + cl) * 33 + m] + Pf[(1 * 128 + cl) * 33 + m]) +
                 (Pf[(2 * 128 + cl) * 33 + m] + Pf[(3 * 128 + cl) * 33 + m]));
      xv[j] = (short)f2b(xq[j] - s * rL);
    }
    *(s16x8*)&xs2[(size_t)(qmt * 32 + m) * 266 + qcs * 128 + c8 * 8] = xv;
  }
  __syncthreads();  // xs2 complete
  // ---- epilogue B: fused LBR conv + BN + ReLU + residual (ex-k_lbr) --------
  int o0 = w * 32;  // 8 waves x 32 = all 256 output channels
  s16x8 wf[16];
#pragma unroll
  for (int kc = 0; kc < 16; kc++)
    wf[kc] = *(const s16x8*)&Wcat[(size_t)(320 + o0 + a) * 256 + kc * 16 + 8 * g];
#pragma unroll
  for (int nsub = 0; nsub < 2; nsub++) {
    f32x16 ac2 = fz16();
#pragma unroll
    for (int kc = 0; kc < 16; kc++) {
      s16x8 xf = *(const s16x8*)&xs2[(size_t)(nsub * 32 + a) * 266 + kc * 16 + 8 * g];
      ac2 = MFMA32(wf[kc], xf, ac2);  // D[o][n]
    }
    int n = m0 + nsub * 32 + a;
#pragma unroll
    for (int r = 0; r < 16; r++) {
      int o = o0 + (r & 3) + 8 * (r >> 2) + 4 * g;
      float v = ac2[r] * sdL[o] + sdL[256 + o];
      v = fmaxf(v, 0.0f);
      ob[(size_t)o * Nn + n] = xb[(size_t)o * Nn + n] + v;  // x re-read: L2-hot
    }
  }
}

extern "C" void kernel_launch(void* const* d_in, const int* in_sizes, int n_in,
                              void* d_out, int out_size, void* d_ws, size_t ws_size,
                              hipStream_t stream) {
  (void)in_sizes; (void)n_in; (void)out_size; (void)ws_size;
  const float* x = (const float*)d_in[0];
  const float* wqk = (const float*)d_in[1];
  const float* wv = (const float*)d_in[2];
  const float* bv = (const float*)d_in[3];
  const float* wlbr = (const float*)d_in[4];
  const float* blbr = (const float*)d_in[5];
  const float* gamma = (const float*)d_in[6];
  const float* beta = (const float*)d_in[7];
  const float* mean = (const float*)d_in[8];
  const float* var = (const float*)d_in[9];
  char* ws = (char*)d_ws;
  // ws layout
  unsigned short* qkT = (unsigned short*)ws;               // 4*4096*64*2  = 2,097,152
  unsigned short* Vf = (unsigned short*)(ws + 2097152);    // 4*1048576*2 = 8,388,608 (frag-major)
  float* nrm = (float*)(ws + 10485760);                    // 16384 f32 (ex-xT space)
  float* sd = (float*)(ws + 18874368);                     // 2,048
  unsigned short* Wcat = (unsigned short*)(ws + 18876416); // 576*256*2 = 294,912
  float* out = (float*)d_out;

  k_prep<<<dim3(577), dim3(256), 0, stream>>>(wqk, wv, wlbr, blbr, gamma, beta,
                                              mean, var, Wcat, sd);
  k_proj<<<dim3(512), dim3(640), 0, stream>>>(x, Wcat, bv, qkT, Vf, nrm);
  k_attn<<<dim3(256), dim3(512), 0, stream>>>(qkT, Vf, nrm, Wcat, sd, x, out);
}

// Round 10
// 92.515 us; speedup vs baseline: 1.1856x; 1.1856x over previous
//
#include <hip/hip_runtime.h>
#include <hip/hip_bf16.h>
#include <stdint.h>
#include <math.h>

#define Bq 4
#define Cc 256
#define Nn 4096
#define CQ 64
// 0.25 (=C^-0.25 per side) * sqrt(log2 e), folded into w_qk cast
#define QKSCALE 0.30028060219661246f

typedef short s16x4 __attribute__((ext_vector_type(4)));
typedef short s16x8 __attribute__((ext_vector_type(8)));
typedef unsigned int u32x4 __attribute__((ext_vector_type(4)));
typedef float f32x16 __attribute__((ext_vector_type(16)));

#define MFMA32(a,b,c) __builtin_amdgcn_mfma_f32_32x32x16_bf16((a),(b),(c),0,0,0)

static __device__ __forceinline__ unsigned short f2b(float f) {
  unsigned int u = __float_as_uint(f);
  u += 0x7FFFu + ((u >> 16) & 1u);   // RNE
  return (unsigned short)(u >> 16);
}

static __device__ __forceinline__ unsigned short f2bh(float f) {
  __hip_bfloat16 h = __float2bfloat16(f);
  return __builtin_bit_cast(unsigned short, h);
}

static __device__ __forceinline__ float b2f(unsigned short u) {
  return __uint_as_float(((unsigned int)u) << 16);
}

static __device__ __forceinline__ float fexp2(float x) {
#if __has_builtin(__builtin_amdgcn_exp2f)
  return __builtin_amdgcn_exp2f(x);
#else
  return exp2f(x);
#endif
}

static __device__ __forceinline__ f32x16 fz16() {
  f32x16 z;
#pragma unroll
  for (int i = 0; i < 16; i++) z[i] = 0.0f;
  return z;
}

static __device__ __forceinline__ float sum16(f32x16 E) {
  return (((E[0] + E[1]) + (E[2] + E[3])) + ((E[4] + E[5]) + (E[6] + E[7]))) +
         (((E[8] + E[9]) + (E[10] + E[11])) + ((E[12] + E[13]) + (E[14] + E[15])));
}

// ---------------- K0: weight cast + BN precompute ---------------------------
// Keep as separate kernel: R24 showed inlining multiplies the once-per-launch
// cast by grid size (160MB+64MB extra L2 reads).
__global__ __launch_bounds__(256) void k_prep(
    const float* __restrict__ wqk, const float* __restrict__ wv,
    const float* __restrict__ wlbr, const float* __restrict__ blbr,
    const float* __restrict__ gamma, const float* __restrict__ beta,
    const float* __restrict__ mean, const float* __restrict__ var,
    unsigned short* __restrict__ Wcat, float* __restrict__ sd) {
  int bx = blockIdx.x, t = threadIdx.x;
  if (bx < 576) {
    float v;
    if (bx < 64) v = wqk[bx * 256 + t] * QKSCALE;
    else if (bx < 320) v = wv[(bx - 64) * 256 + t];
    else v = wlbr[(bx - 320) * 256 + t];
    Wcat[bx * 256 + t] = f2b(v);
  } else {
    float s = gamma[t] * rsqrtf(var[t] + 1e-5f);
    sd[t] = s;
    sd[256 + t] = beta[t] + (blbr[t] - mean[t]) * s;
  }
}

// ---------------- K1: fused transpose + projections + qk row-norms ----------
// V written fragment-major Vf[b][ntile32][kk][g][c][j] (R15-verified).
__global__ __launch_bounds__(640) void k_proj(const float* __restrict__ x,
                                              const unsigned short* __restrict__ Wcat,
                                              const float* __restrict__ bv,
                                              unsigned short* __restrict__ qkT,
                                              unsigned short* __restrict__ Vf,
                                              float* __restrict__ nrm) {
  __shared__ unsigned short xs[32 * 264];  // [32 n][256 c], stride 264
  __shared__ float npart[64];              // [2 qwave][32 n] norm partials
  int bx = blockIdx.x;
  int b = bx >> 7;
  int ntile = bx & 127;
  int n0 = ntile * 32;
  int t = threadIdx.x;
  const float* xb = x + (size_t)b * Cc * Nn;
  // stage: transpose + cast. chunk u: c = u>>2, j = (u&3)*8 (8 n-floats)
  for (int u = t; u < 1024; u += 640) {
    int c = u >> 2, j = (u & 3) * 8;
    const float* src = &xb[(size_t)c * Nn + n0 + j];
    float4 v0 = *(const float4*)src;
    float4 v1 = *(const float4*)(src + 4);
    xs[(j + 0) * 264 + c] = f2b(v0.x);
    xs[(j + 1) * 264 + c] = f2b(v0.y);
    xs[(j + 2) * 264 + c] = f2b(v0.z);
    xs[(j + 3) * 264 + c] = f2b(v0.w);
    xs[(j + 4) * 264 + c] = f2b(v1.x);
    xs[(j + 5) * 264 + c] = f2b(v1.y);
    xs[(j + 6) * 264 + c] = f2b(v1.z);
    xs[(j + 7) * 264 + c] = f2b(v1.w);
  }
  int w = t >> 6, a = t & 31, g = (t >> 5) & 1;
  bool isqk = (w >= 8);
  int row0 = isqk ? (w - 8) * 32 : 64 + w * 32;  // Wcat row base
  s16x8 wf[16];
#pragma unroll
  for (int kc = 0; kc < 16; kc++)
    wf[kc] = *(const s16x8*)&Wcat[(size_t)(row0 + a) * 256 + kc * 16 + 8 * g];
  __syncthreads();
  f32x16 acc = fz16();
#pragma unroll
  for (int kc = 0; kc < 16; kc++) {
    s16x8 xf = *(const s16x8*)&xs[a * 264 + kc * 16 + 8 * g];
    acc = MFMA32(xf, wf[kc], acc);  // D[n][row0-row] (operand-swap, both paths)
  }
  if (isqk) {
    unsigned short* dst = qkT + ((size_t)b * Nn + n0) * CQ;
    int q0 = row0;
#pragma unroll
    for (int r = 0; r < 16; r++) {
      int n = (r & 3) + 8 * (r >> 2) + 4 * g;
      dst[(size_t)n * CQ + q0 + a] = f2b(acc[r]);
    }
    // row-norm partials: sum_q acc[r]^2 over this wave's 32 q (lanes)
    float s2[16];
#pragma unroll
    for (int r = 0; r < 16; r++) {
      float v = acc[r] * acc[r];
#pragma unroll
      for (int off = 1; off < 32; off <<= 1) v += __shfl_xor(v, off, 64);
      s2[r] = v;
    }
    if ((t & 31) == 0) {  // lanes 0 (g=0) and 32 (g=1) write their 16 n's
#pragma unroll
      for (int r = 0; r < 16; r++) {
        int n = (r & 3) + 8 * (r >> 2) + 4 * g;
        npart[(w - 8) * 32 + n] = s2[r];
      }
    }
  } else {
    int c0 = row0 - 64;
    float bvv = bv[c0 + a];
    // acc[r] = V[n_local = sigma0(r&7) + 16*(r>>3) + 4g][c0+a]
    s16x8 vlo, vhi;
#pragma unroll
    for (int r = 0; r < 8; r++) {
      vlo[r] = (short)f2b(acc[r] + bvv);
      vhi[r] = (short)f2b(acc[8 + r] + bvv);
    }
    // Vf[b][ntile][kk][g][c][j]: strides (shorts) j:1, c:8, g:2048, kk:4096, ntile:8192
    unsigned short* dstF =
        Vf + ((size_t)(b * 128 + ntile) * 4 + g) * 2048 + (size_t)(c0 + a) * 8;
    *(s16x8*)dstF = vlo;             // kk=0
    *(s16x8*)(dstF + 4096) = vhi;    // kk=1
  }
  __syncthreads();  // npart ready
  if (t < 32) nrm[(size_t)b * Nn + n0 + t] = sqrtf(npart[t] + npart[32 + t]);
}

// ---------------- K2: flash attention (R17 loop) + fused LBR epilogue -------
// FINAL structure (R23). Loop ledger: R18 E-pingpong (spill), R19 rotation
// (exposed V latency), R20 SGB pin (over-constraint), R21 repartition (2x V
// L2 traffic), R24 de-phase (neutral) + inline casts (per-block cost), R25
// setprio (sched-region boundaries -> spill). All regressed vs this loop.
__global__ __launch_bounds__(512, 2) void k_attn(const unsigned short* __restrict__ qkT,
                                                 const unsigned short* __restrict__ Vf,
                                                 const float* __restrict__ nrm,
                                                 const unsigned short* __restrict__ Wcat,
                                                 const float* __restrict__ sd,
                                                 const float* __restrict__ x,
                                                 float* __restrict__ out) {
  __shared__ __align__(16) float Pf[4 * 128 * 33];   // [ns][c_local 128][m 32+pad]
  __shared__ float Ls[4 * 64];                       // [ns][m-local 0..63]
  __shared__ unsigned short xs2[64 * 266];           // xr tile [64 n][256 c]+pad
  __shared__ float sdL[512];                         // BN scale/shift
  __shared__ float wmx[8];
  int bx = blockIdx.x;
  int id = ((bx & 7) << 5) | (bx >> 3);  // XCD swizzle, 256 = 8 x 32, bijective
  int b = id >> 6;
  int m0 = (id & 63) * 64;
  int t = threadIdx.x;
  int w = t >> 6, a = t & 31, g = (t >> 5) & 1;
  int cs = w >> 2, ns = w & 3;  // same-SIMD waves share ns -> Q frags L1-hot
  const unsigned short* qkTb = qkT + (size_t)b * Nn * CQ;
  sdL[t < 512 ? t : 0] = sd[t < 512 ? t : 0];
  // block-local batch max of nrm
  const float* nrmb = nrm + (size_t)b * Nn;
  float lm = 0.0f;
#pragma unroll
  for (int i = 0; i < 8; i++) lm = fmaxf(lm, nrmb[t + i * 512]);
#pragma unroll
  for (int off = 1; off < 64; off <<= 1) lm = fmaxf(lm, __shfl_xor(lm, off, 64));
  if ((t & 63) == 0) wmx[w] = lm;
  __syncthreads();
  float mxf = fmaxf(fmaxf(fmaxf(wmx[0], wmx[1]), fmaxf(wmx[2], wmx[3])),
                    fmaxf(fmaxf(wmx[4], wmx[5]), fmaxf(wmx[6], wmx[7])));
  // B operands: columns m0..m0+31 (mt=0) and m0+32..m0+63 (mt=1)
  s16x8 Bq0[4], Bq1[4];
#pragma unroll
  for (int kc = 0; kc < 4; kc++) {
    Bq0[kc] = *(const s16x8*)&qkTb[(size_t)(m0 + a) * CQ + kc * 16 + 8 * g];
    Bq1[kc] = *(const s16x8*)&qkTb[(size_t)(m0 + 32 + a) * CQ + kc * 16 + 8 * g];
  }
  // Cauchy-Schwarz column bound: Mh >= max_n E[n,mcol]
  float Mh0 = nrmb[m0 + a] * mxf + 0.01f;
  float Mh1 = nrmb[m0 + 32 + a] * mxf + 0.01f;
  // V fragment base for this lane: Vf[b][nt][kk][g][c][j], c = cs*128 + ct*32 + a
  const unsigned short* Vc = Vf + (size_t)b * 1048576 + (size_t)g * 2048 +
                             (size_t)(cs * 128 + a) * 8;
  f32x16 acc[8];  // [mt*4+ct]: O^T partial, m = m0+mt*32+row, c = cs*128+ct*32+a
#pragma unroll
  for (int i = 0; i < 8; i++) acc[i] = fz16();
  float Lp0 = 0.0f, Lp1 = 0.0f;
  s16x8 qf[4];  // A operand: Q rows nt*32 + a (prefetched one tile ahead)
#pragma unroll
  for (int kc = 0; kc < 4; kc++)
    qf[kc] = *(const s16x8*)&qkTb[(size_t)(ns * 32 + a) * CQ + kc * 16 + 8 * g];
#pragma unroll 1
  for (int nt = ns; nt < 128; nt += 4) {
    const unsigned short* Vt = Vc + (size_t)nt * 8192;
    f32x16 E0 = fz16(), E1 = fz16();
#pragma unroll
    for (int kc = 0; kc < 4; kc++) E0 = MFMA32(qf[kc], Bq0[kc], E0);
    s16x8 va0, va1, va2, va3;  // (ct0,kk0) (ct0,kk1) (ct1,kk0) (ct1,kk1)
    va0 = *(const s16x8*)&Vt[0];
    va1 = *(const s16x8*)&Vt[4096];
    va2 = *(const s16x8*)&Vt[256];
    va3 = *(const s16x8*)&Vt[4096 + 256];
#pragma unroll
    for (int kc = 0; kc < 4; kc++) E1 = MFMA32(qf[kc], Bq1[kc], E1);
    int ntn = (nt + 4) & 127;  // wrap on last iter: harmless dummy reload
#pragma unroll
    for (int kc = 0; kc < 4; kc++)
      qf[kc] = *(const s16x8*)&qkTb[(size_t)(ntn * 32 + a) * CQ + kc * 16 + 8 * g];
    // softmax mt=0 (E dies into packed P -> keeps transient VGPR low)
#pragma unroll
    for (int r = 0; r < 16; r++) E0[r] = fexp2(E0[r] - Mh0);
    Lp0 += sum16(E0);
    s16x8 p00, p01;
#pragma unroll
    for (int j = 0; j < 8; j++) {
      p00[j] = (short)f2bh(E0[j]);
      p01[j] = (short)f2bh(E0[8 + j]);
    }
    // softmax mt=1
#pragma unroll
    for (int r = 0; r < 16; r++) E1[r] = fexp2(E1[r] - Mh1);
    Lp1 += sum16(E1);
    s16x8 p10, p11;
#pragma unroll
    for (int j = 0; j < 8; j++) {
      p10[j] = (short)f2bh(E1[j]);
      p11[j] = (short)f2bh(E1[8 + j]);
    }
    // PV ct0/ct1: kk0 round then kk1 round (8 independent acc chains)
    acc[0] = MFMA32(p00, va0, acc[0]);
    acc[4] = MFMA32(p10, va0, acc[4]);
    acc[1] = MFMA32(p00, va2, acc[1]);
    acc[5] = MFMA32(p10, va2, acc[5]);
    acc[0] = MFMA32(p01, va1, acc[0]);
    acc[4] = MFMA32(p11, va1, acc[4]);
    acc[1] = MFMA32(p01, va3, acc[1]);
    acc[5] = MFMA32(p11, va3, acc[5]);
    s16x8 vb0, vb1, vb2, vb3;  // ct2, ct3
    vb0 = *(const s16x8*)&Vt[512];
    vb1 = *(const s16x8*)&Vt[4096 + 512];
    vb2 = *(const s16x8*)&Vt[768];
    vb3 = *(const s16x8*)&Vt[4096 + 768];
    acc[2] = MFMA32(p00, vb0, acc[2]);
    acc[6] = MFMA32(p10, vb0, acc[6]);
    acc[3] = MFMA32(p00, vb2, acc[3]);
    acc[7] = MFMA32(p10, vb2, acc[7]);
    acc[2] = MFMA32(p01, vb1, acc[2]);
    acc[6] = MFMA32(p11, vb1, acc[6]);
    acc[3] = MFMA32(p01, vb3, acc[3]);
    acc[7] = MFMA32(p11, vb3, acc[7]);
  }
  // ---- epilogue A: combine ns-partials per (mt,cs) quadrant -> xr in LDS ----
  float Lw0 = Lp0 + __shfl_xor(Lp0, 32, 64);  // sum both g-halves (n rows)
  float Lw1 = Lp1 + __shfl_xor(Lp1, 32, 64);
  if (cs == 0 && (t & 63) < 32) {  // cs=1 partials are identical; write once
    Ls[ns * 64 + a] = Lw0;
    Ls[ns * 64 + 32 + a] = Lw1;
  }
  const float* xb = x + (size_t)b * Cc * Nn;
  float* ob = out + (size_t)b * Cc * Nn;
#pragma unroll
  for (int q = 0; q < 4; q++) {
    int qmt = q >> 1, qcs = q & 1;
    int m = t & 31, c8 = t >> 5;  // c8 in 0..15
    // x loads for this quadrant issued BEFORE the syncs: latency hidden
    float xq[8];
#pragma unroll
    for (int j = 0; j < 8; j++)
      xq[j] = xb[(size_t)(qcs * 128 + c8 * 8 + j) * Nn + m0 + qmt * 32 + m];
    __syncthreads();  // also guards Ls on q=0; prior reads done before rewrite
    if (cs == qcs) {
#pragma unroll
      for (int ct = 0; ct < 4; ct++) {
        float* dst = &Pf[(size_t)(ns * 128 + ct * 32 + a) * 33];
        f32x16 A = acc[qmt * 4 + ct];
#pragma unroll
        for (int r = 0; r < 16; r++) {
          int mrow = (r & 3) + 8 * (r >> 2) + 4 * g;
          dst[mrow] = A[r];  // bank = (a + 4g) mod 32 -> 2-way, free
        }
      }
    }
    __syncthreads();
    // combine: 512 threads x 8 outputs; rows m0+qmt*32+m, cols qcs*128+..
    float rL = 1.0f / (((Ls[qmt * 32 + m] + Ls[64 + qmt * 32 + m]) +
                        (Ls[128 + qmt * 32 + m] + Ls[192 + qmt * 32 + m])));
    s16x8 xv;
#pragma unroll
    for (int j = 0; j < 8; j++) {
      int cl = qcs * 128 + c8 * 8 + j;
      float s = ((Pf[(0 * 128 + cl) * 33 + m] + Pf[(1 * 128 + cl) * 33 + m]) +
                 (Pf[(2 * 128 + cl) * 33 + m] + Pf[(3 * 128 + cl) * 33 + m]));
      xv[j] = (short)f2b(xq[j] - s * rL);
    }
    *(s16x8*)&xs2[(size_t)(qmt * 32 + m) * 266 + qcs * 128 + c8 * 8] = xv;
  }
  __syncthreads();  // xs2 complete
  // ---- epilogue B: fused LBR conv + BN + ReLU + residual (ex-k_lbr) --------
  int o0 = w * 32;  // 8 waves x 32 = all 256 output channels
  s16x8 wf[16];
#pragma unroll
  for (int kc = 0; kc < 16; kc++)
    wf[kc] = *(const s16x8*)&Wcat[(size_t)(320 + o0 + a) * 256 + kc * 16 + 8 * g];
#pragma unroll
  for (int nsub = 0; nsub < 2; nsub++) {
    f32x16 ac2 = fz16();
#pragma unroll
    for (int kc = 0; kc < 16; kc++) {
      s16x8 xf = *(const s16x8*)&xs2[(size_t)(nsub * 32 + a) * 266 + kc * 16 + 8 * g];
      ac2 = MFMA32(wf[kc], xf, ac2);  // D[o][n]
    }
    int n = m0 + nsub * 32 + a;
#pragma unroll
    for (int r = 0; r < 16; r++) {
      int o = o0 + (r & 3) + 8 * (r >> 2) + 4 * g;
      float v = ac2[r] * sdL[o] + sdL[256 + o];
      v = fmaxf(v, 0.0f);
      ob[(size_t)o * Nn + n] = xb[(size_t)o * Nn + n] + v;  // x re-read: L2-hot
    }
  }
}

extern "C" void kernel_launch(void* const* d_in, const int* in_sizes, int n_in,
                              void* d_out, int out_size, void* d_ws, size_t ws_size,
                              hipStream_t stream) {
  (void)in_sizes; (void)n_in; (void)out_size; (void)ws_size;
  const float* x = (const float*)d_in[0];
  const float* wqk = (const float*)d_in[1];
  const float* wv = (const float*)d_in[2];
  const float* bv = (const float*)d_in[3];
  const float* wlbr = (const float*)d_in[4];
  const float* blbr = (const float*)d_in[5];
  const float* gamma = (const float*)d_in[6];
  const float* beta = (const float*)d_in[7];
  const float* mean = (const float*)d_in[8];
  const float* var = (const float*)d_in[9];
  char* ws = (char*)d_ws;
  // ws layout
  unsigned short* qkT = (unsigned short*)ws;               // 4*4096*64*2  = 2,097,152
  unsigned short* Vf = (unsigned short*)(ws + 2097152);    // 4*1048576*2 = 8,388,608 (frag-major)
  float* nrm = (float*)(ws + 10485760);                    // 16384 f32 (ex-xT space)
  float* sd = (float*)(ws + 18874368);                     // 2,048
  unsigned short* Wcat = (unsigned short*)(ws + 18876416); // 576*256*2 = 294,912
  float* out = (float*)d_out;

  k_prep<<<dim3(577), dim3(256), 0, stream>>>(wqk, wv, wlbr, blbr, gamma, beta,
                                              mean, var, Wcat, sd);
  k_proj<<<dim3(512), dim3(640), 0, stream>>>(x, Wcat, bv, qkT, Vf, nrm);
  k_attn<<<dim3(256), dim3(512), 0, stream>>>(qkT, Vf, nrm, Wcat, sd, x, out);
}

// Round 11
// 89.569 us; speedup vs baseline: 1.2246x; 1.0329x over previous
//
#include <hip/hip_runtime.h>
#include <hip/hip_bf16.h>
#include <stdint.h>
#include <math.h>

#define Bq 4
#define Cc 256
#define Nn 4096
#define CQ 64
// 0.25 (=C^-0.25 per side) * sqrt(log2 e), folded into w_qk cast
#define QKSCALE 0.30028060219661246f

typedef short s16x4 __attribute__((ext_vector_type(4)));
typedef short s16x8 __attribute__((ext_vector_type(8)));
typedef unsigned int u32x4 __attribute__((ext_vector_type(4)));
typedef float f32x16 __attribute__((ext_vector_type(16)));

#define MFMA32(a,b,c) __builtin_amdgcn_mfma_f32_32x32x16_bf16((a),(b),(c),0,0,0)

static __device__ __forceinline__ unsigned short f2b(float f) {
  unsigned int u = __float_as_uint(f);
  u += 0x7FFFu + ((u >> 16) & 1u);   // RNE
  return (unsigned short)(u >> 16);
}

static __device__ __forceinline__ unsigned short f2bh(float f) {
  __hip_bfloat16 h = __float2bfloat16(f);  // native v_cvt RNE: 1 VALU op
  return __builtin_bit_cast(unsigned short, h);
}

static __device__ __forceinline__ float b2f(unsigned short u) {
  return __uint_as_float(((unsigned int)u) << 16);
}

static __device__ __forceinline__ float fexp2(float x) {
#if __has_builtin(__builtin_amdgcn_exp2f)
  return __builtin_amdgcn_exp2f(x);
#else
  return exp2f(x);
#endif
}

static __device__ __forceinline__ f32x16 fz16() {
  f32x16 z;
#pragma unroll
  for (int i = 0; i < 16; i++) z[i] = 0.0f;
  return z;
}

static __device__ __forceinline__ float sum16(f32x16 E) {
  return (((E[0] + E[1]) + (E[2] + E[3])) + ((E[4] + E[5]) + (E[6] + E[7]))) +
         (((E[8] + E[9]) + (E[10] + E[11])) + ((E[12] + E[13]) + (E[14] + E[15])));
}

// ---------------- K0: weight cast + BN precompute ---------------------------
// Keep as separate kernel: R24 showed inlining multiplies the once-per-launch
// cast by grid size (160MB+64MB extra L2 reads).
__global__ __launch_bounds__(256) void k_prep(
    const float* __restrict__ wqk, const float* __restrict__ wv,
    const float* __restrict__ wlbr, const float* __restrict__ blbr,
    const float* __restrict__ gamma, const float* __restrict__ beta,
    const float* __restrict__ mean, const float* __restrict__ var,
    unsigned short* __restrict__ Wcat, float* __restrict__ sd) {
  int bx = blockIdx.x, t = threadIdx.x;
  if (bx < 576) {
    float v;
    if (bx < 64) v = wqk[bx * 256 + t] * QKSCALE;
    else if (bx < 320) v = wv[(bx - 64) * 256 + t];
    else v = wlbr[(bx - 320) * 256 + t];
    Wcat[bx * 256 + t] = f2b(v);
  } else {
    float s = gamma[t] * rsqrtf(var[t] + 1e-5f);
    sd[t] = s;
    sd[256 + t] = beta[t] + (blbr[t] - mean[t]) * s;
  }
}

// ---------------- K1: fused transpose + projections + qk row-norms ----------
// R27: n-tile doubled to 64 (grid 512->256): halves the 84MB Wcat fragment
// re-read and the launch/block overhead; each wave computes both n-subtiles
// (2x MFMA per weight fragment load). Staging cast f2b -> f2bh (native
// v_cvt RNE, 1 VALU vs 3, bit-identical for finite input). Vf layout
// unchanged: ntile64 = two consecutive ntile32 records (R15-verified frags).
__global__ __launch_bounds__(640) void k_proj(const float* __restrict__ x,
                                              const unsigned short* __restrict__ Wcat,
                                              const float* __restrict__ bv,
                                              unsigned short* __restrict__ qkT,
                                              unsigned short* __restrict__ Vf,
                                              float* __restrict__ nrm) {
  __shared__ unsigned short xs[64 * 264];  // [64 n][256 c], stride 264
  __shared__ float npart[128];             // [2 qwave][64 n] norm partials
  int bx = blockIdx.x;
  int b = bx >> 6;
  int ntile = bx & 63;
  int n0 = ntile * 64;
  int t = threadIdx.x;
  const float* xb = x + (size_t)b * Cc * Nn;
  // stage: transpose + cast. chunk u: c = u>>3, j = (u&7)*8 (8 n-floats)
  for (int u = t; u < 2048; u += 640) {
    int c = u >> 3, j = (u & 7) * 8;
    const float* src = &xb[(size_t)c * Nn + n0 + j];
    float4 v0 = *(const float4*)src;
    float4 v1 = *(const float4*)(src + 4);
    xs[(j + 0) * 264 + c] = f2bh(v0.x);
    xs[(j + 1) * 264 + c] = f2bh(v0.y);
    xs[(j + 2) * 264 + c] = f2bh(v0.z);
    xs[(j + 3) * 264 + c] = f2bh(v0.w);
    xs[(j + 4) * 264 + c] = f2bh(v1.x);
    xs[(j + 5) * 264 + c] = f2bh(v1.y);
    xs[(j + 6) * 264 + c] = f2bh(v1.z);
    xs[(j + 7) * 264 + c] = f2bh(v1.w);
  }
  int w = t >> 6, a = t & 31, g = (t >> 5) & 1;
  bool isqk = (w >= 8);
  int row0 = isqk ? (w - 8) * 32 : 64 + w * 32;  // Wcat row base
  s16x8 wf[16];
#pragma unroll
  for (int kc = 0; kc < 16; kc++)
    wf[kc] = *(const s16x8*)&Wcat[(size_t)(row0 + a) * 256 + kc * 16 + 8 * g];
  __syncthreads();
  f32x16 acc0 = fz16(), acc1 = fz16();  // n-subtiles 0..31 / 32..63
#pragma unroll
  for (int kc = 0; kc < 16; kc++) {
    s16x8 xf0 = *(const s16x8*)&xs[a * 264 + kc * 16 + 8 * g];
    s16x8 xf1 = *(const s16x8*)&xs[(32 + a) * 264 + kc * 16 + 8 * g];
    acc0 = MFMA32(xf0, wf[kc], acc0);  // D[n][row0-row] (operand-swap)
    acc1 = MFMA32(xf1, wf[kc], acc1);
  }
  if (isqk) {
    unsigned short* dst = qkT + ((size_t)b * Nn + n0) * CQ;
    int q0 = row0;
#pragma unroll
    for (int r = 0; r < 16; r++) {
      int n = (r & 3) + 8 * (r >> 2) + 4 * g;
      dst[(size_t)n * CQ + q0 + a] = f2bh(acc0[r]);
      dst[(size_t)(32 + n) * CQ + q0 + a] = f2bh(acc1[r]);
    }
    // row-norm partials: sum_q acc[r]^2 over this wave's 32 q (lanes)
    float s20[16], s21[16];
#pragma unroll
    for (int r = 0; r < 16; r++) {
      float v0 = acc0[r] * acc0[r];
      float v1 = acc1[r] * acc1[r];
#pragma unroll
      for (int off = 1; off < 32; off <<= 1) {
        v0 += __shfl_xor(v0, off, 64);
        v1 += __shfl_xor(v1, off, 64);
      }
      s20[r] = v0;
      s21[r] = v1;
    }
    if ((t & 31) == 0) {  // lanes 0 (g=0) and 32 (g=1) write their 16 n's
#pragma unroll
      for (int r = 0; r < 16; r++) {
        int n = (r & 3) + 8 * (r >> 2) + 4 * g;
        npart[(w - 8) * 64 + n] = s20[r];
        npart[(w - 8) * 64 + 32 + n] = s21[r];
      }
    }
  } else {
    int c0 = row0 - 64;
    float bvv = bv[c0 + a];
    // accS[r] = V[n_local = sigma0(r&7) + 16*(r>>3) + 4g][c0+a] of subtile S
#pragma unroll
    for (int sub = 0; sub < 2; sub++) {
      f32x16 A = sub ? acc1 : acc0;
      s16x8 vlo, vhi;
#pragma unroll
      for (int r = 0; r < 8; r++) {
        vlo[r] = (short)f2bh(A[r] + bvv);
        vhi[r] = (short)f2bh(A[8 + r] + bvv);
      }
      // Vf[b][ntile32][kk][g][c][j]; ntile32 = 2*ntile + sub
      unsigned short* dstF =
          Vf + ((size_t)(b * 128 + 2 * ntile + sub) * 4 + g) * 2048 +
          (size_t)(c0 + a) * 8;
      *(s16x8*)dstF = vlo;             // kk=0
      *(s16x8*)(dstF + 4096) = vhi;    // kk=1
    }
  }
  __syncthreads();  // npart ready
  if (t < 64) nrm[(size_t)b * Nn + n0 + t] = sqrtf(npart[t] + npart[64 + t]);
}

// ---------------- K2: flash attention (R17 loop) + fused LBR epilogue -------
// FINAL structure (R23), FROZEN. Loop ledger: R18 E-pingpong (spill), R19
// rotation (exposed V latency), R20 SGB pin (over-constraint), R21
// repartition (2x V L2 traffic), R24 de-phase (neutral) + inline casts
// (per-block cost), R25 setprio (sched-region boundaries -> spill). All
// regressed vs this loop.
__global__ __launch_bounds__(512, 2) void k_attn(const unsigned short* __restrict__ qkT,
                                                 const unsigned short* __restrict__ Vf,
                                                 const float* __restrict__ nrm,
                                                 const unsigned short* __restrict__ Wcat,
                                                 const float* __restrict__ sd,
                                                 const float* __restrict__ x,
                                                 float* __restrict__ out) {
  __shared__ __align__(16) float Pf[4 * 128 * 33];   // [ns][c_local 128][m 32+pad]
  __shared__ float Ls[4 * 64];                       // [ns][m-local 0..63]
  __shared__ unsigned short xs2[64 * 266];           // xr tile [64 n][256 c]+pad
  __shared__ float sdL[512];                         // BN scale/shift
  __shared__ float wmx[8];
  int bx = blockIdx.x;
  int id = ((bx & 7) << 5) | (bx >> 3);  // XCD swizzle, 256 = 8 x 32, bijective
  int b = id >> 6;
  int m0 = (id & 63) * 64;
  int t = threadIdx.x;
  int w = t >> 6, a = t & 31, g = (t >> 5) & 1;
  int cs = w >> 2, ns = w & 3;  // same-SIMD waves share ns -> Q frags L1-hot
  const unsigned short* qkTb = qkT + (size_t)b * Nn * CQ;
  sdL[t < 512 ? t : 0] = sd[t < 512 ? t : 0];
  // block-local batch max of nrm
  const float* nrmb = nrm + (size_t)b * Nn;
  float lm = 0.0f;
#pragma unroll
  for (int i = 0; i < 8; i++) lm = fmaxf(lm, nrmb[t + i * 512]);
#pragma unroll
  for (int off = 1; off < 64; off <<= 1) lm = fmaxf(lm, __shfl_xor(lm, off, 64));
  if ((t & 63) == 0) wmx[w] = lm;
  __syncthreads();
  float mxf = fmaxf(fmaxf(fmaxf(wmx[0], wmx[1]), fmaxf(wmx[2], wmx[3])),
                    fmaxf(fmaxf(wmx[4], wmx[5]), fmaxf(wmx[6], wmx[7])));
  // B operands: columns m0..m0+31 (mt=0) and m0+32..m0+63 (mt=1)
  s16x8 Bq0[4], Bq1[4];
#pragma unroll
  for (int kc = 0; kc < 4; kc++) {
    Bq0[kc] = *(const s16x8*)&qkTb[(size_t)(m0 + a) * CQ + kc * 16 + 8 * g];
    Bq1[kc] = *(const s16x8*)&qkTb[(size_t)(m0 + 32 + a) * CQ + kc * 16 + 8 * g];
  }
  // Cauchy-Schwarz column bound: Mh >= max_n E[n,mcol]
  float Mh0 = nrmb[m0 + a] * mxf + 0.01f;
  float Mh1 = nrmb[m0 + 32 + a] * mxf + 0.01f;
  // V fragment base for this lane: Vf[b][nt][kk][g][c][j], c = cs*128 + ct*32 + a
  const unsigned short* Vc = Vf + (size_t)b * 1048576 + (size_t)g * 2048 +
                             (size_t)(cs * 128 + a) * 8;
  f32x16 acc[8];  // [mt*4+ct]: O^T partial, m = m0+mt*32+row, c = cs*128+ct*32+a
#pragma unroll
  for (int i = 0; i < 8; i++) acc[i] = fz16();
  float Lp0 = 0.0f, Lp1 = 0.0f;
  s16x8 qf[4];  // A operand: Q rows nt*32 + a (prefetched one tile ahead)
#pragma unroll
  for (int kc = 0; kc < 4; kc++)
    qf[kc] = *(const s16x8*)&qkTb[(size_t)(ns * 32 + a) * CQ + kc * 16 + 8 * g];
#pragma unroll 1
  for (int nt = ns; nt < 128; nt += 4) {
    const unsigned short* Vt = Vc + (size_t)nt * 8192;
    f32x16 E0 = fz16(), E1 = fz16();
#pragma unroll
    for (int kc = 0; kc < 4; kc++) E0 = MFMA32(qf[kc], Bq0[kc], E0);
    s16x8 va0, va1, va2, va3;  // (ct0,kk0) (ct0,kk1) (ct1,kk0) (ct1,kk1)
    va0 = *(const s16x8*)&Vt[0];
    va1 = *(const s16x8*)&Vt[4096];
    va2 = *(const s16x8*)&Vt[256];
    va3 = *(const s16x8*)&Vt[4096 + 256];
#pragma unroll
    for (int kc = 0; kc < 4; kc++) E1 = MFMA32(qf[kc], Bq1[kc], E1);
    int ntn = (nt + 4) & 127;  // wrap on last iter: harmless dummy reload
#pragma unroll
    for (int kc = 0; kc < 4; kc++)
      qf[kc] = *(const s16x8*)&qkTb[(size_t)(ntn * 32 + a) * CQ + kc * 16 + 8 * g];
    // softmax mt=0 (E dies into packed P -> keeps transient VGPR low)
#pragma unroll
    for (int r = 0; r < 16; r++) E0[r] = fexp2(E0[r] - Mh0);
    Lp0 += sum16(E0);
    s16x8 p00, p01;
#pragma unroll
    for (int j = 0; j < 8; j++) {
      p00[j] = (short)f2bh(E0[j]);
      p01[j] = (short)f2bh(E0[8 + j]);
    }
    // softmax mt=1
#pragma unroll
    for (int r = 0; r < 16; r++) E1[r] = fexp2(E1[r] - Mh1);
    Lp1 += sum16(E1);
    s16x8 p10, p11;
#pragma unroll
    for (int j = 0; j < 8; j++) {
      p10[j] = (short)f2bh(E1[j]);
      p11[j] = (short)f2bh(E1[8 + j]);
    }
    // PV ct0/ct1: kk0 round then kk1 round (8 independent acc chains)
    acc[0] = MFMA32(p00, va0, acc[0]);
    acc[4] = MFMA32(p10, va0, acc[4]);
    acc[1] = MFMA32(p00, va2, acc[1]);
    acc[5] = MFMA32(p10, va2, acc[5]);
    acc[0] = MFMA32(p01, va1, acc[0]);
    acc[4] = MFMA32(p11, va1, acc[4]);
    acc[1] = MFMA32(p01, va3, acc[1]);
    acc[5] = MFMA32(p11, va3, acc[5]);
    s16x8 vb0, vb1, vb2, vb3;  // ct2, ct3
    vb0 = *(const s16x8*)&Vt[512];
    vb1 = *(const s16x8*)&Vt[4096 + 512];
    vb2 = *(const s16x8*)&Vt[768];
    vb3 = *(const s16x8*)&Vt[4096 + 768];
    acc[2] = MFMA32(p00, vb0, acc[2]);
    acc[6] = MFMA32(p10, vb0, acc[6]);
    acc[3] = MFMA32(p00, vb2, acc[3]);
    acc[7] = MFMA32(p10, vb2, acc[7]);
    acc[2] = MFMA32(p01, vb1, acc[2]);
    acc[6] = MFMA32(p11, vb1, acc[6]);
    acc[3] = MFMA32(p01, vb3, acc[3]);
    acc[7] = MFMA32(p11, vb3, acc[7]);
  }
  // ---- epilogue A: combine ns-partials per (mt,cs) quadrant -> xr in LDS ----
  float Lw0 = Lp0 + __shfl_xor(Lp0, 32, 64);  // sum both g-halves (n rows)
  float Lw1 = Lp1 + __shfl_xor(Lp1, 32, 64);
  if (cs == 0 && (t & 63) < 32) {  // cs=1 partials are identical; write once
    Ls[ns * 64 + a] = Lw0;
    Ls[ns * 64 + 32 + a] = Lw1;
  }
  const float* xb = x + (size_t)b * Cc * Nn;
  float* ob = out + (size_t)b * Cc * Nn;
#pragma unroll
  for (int q = 0; q < 4; q++) {
    int qmt = q >> 1, qcs = q & 1;
    int m = t & 31, c8 = t >> 5;  // c8 in 0..15
    // x loads for this quadrant issued BEFORE the syncs: latency hidden
    float xq[8];
#pragma unroll
    for (int j = 0; j < 8; j++)
      xq[j] = xb[(size_t)(qcs * 128 + c8 * 8 + j) * Nn + m0 + qmt * 32 + m];
    __syncthreads();  // also guards Ls on q=0; prior reads done before rewrite
    if (cs == qcs) {
#pragma unroll
      for (int ct = 0; ct < 4; ct++) {
        float* dst = &Pf[(size_t)(ns * 128 + ct * 32 + a) * 33];
        f32x16 A = acc[qmt * 4 + ct];
#pragma unroll
        for (int r = 0; r < 16; r++) {
          int mrow = (r & 3) + 8 * (r >> 2) + 4 * g;
          dst[mrow] = A[r];  // bank = (a + 4g) mod 32 -> 2-way, free
        }
      }
    }
    __syncthreads();
    // combine: 512 threads x 8 outputs; rows m0+qmt*32+m, cols qcs*128+..
    float rL = 1.0f / (((Ls[qmt * 32 + m] + Ls[64 + qmt * 32 + m]) +
                        (Ls[128 + qmt * 32 + m] + Ls[192 + qmt * 32 + m])));
    s16x8 xv;
#pragma unroll
    for (int j = 0; j < 8; j++) {
      int cl = qcs * 128 + c8 * 8 + j;
      float s = ((Pf[(0 * 128 + cl) * 33 + m] + Pf[(1 * 128 + cl) * 33 + m]) +
                 (Pf[(2 * 128 + cl) * 33 + m] + Pf[(3 * 128 + cl) * 33 + m]));
      xv[j] = (short)f2b(xq[j] - s * rL);
    }
    *(s16x8*)&xs2[(size_t)(qmt * 32 + m) * 266 + qcs * 128 + c8 * 8] = xv;
  }
  __syncthreads();  // xs2 complete
  // ---- epilogue B: fused LBR conv + BN + ReLU + residual (ex-k_lbr) --------
  int o0 = w * 32;  // 8 waves x 32 = all 256 output channels
  s16x8 wf[16];
#pragma unroll
  for (int kc = 0; kc < 16; kc++)
    wf[kc] = *(const s16x8*)&Wcat[(size_t)(320 + o0 + a) * 256 + kc * 16 + 8 * g];
#pragma unroll
  for (int nsub = 0; nsub < 2; nsub++) {
    f32x16 ac2 = fz16();
#pragma unroll
    for (int kc = 0; kc < 16; kc++) {
      s16x8 xf = *(const s16x8*)&xs2[(size_t)(nsub * 32 + a) * 266 + kc * 16 + 8 * g];
      ac2 = MFMA32(wf[kc], xf, ac2);  // D[o][n]
    }
    int n = m0 + nsub * 32 + a;
#pragma unroll
    for (int r = 0; r < 16; r++) {
      int o = o0 + (r & 3) + 8 * (r >> 2) + 4 * g;
      float v = ac2[r] * sdL[o] + sdL[256 + o];
      v = fmaxf(v, 0.0f);
      ob[(size_t)o * Nn + n] = xb[(size_t)o * Nn + n] + v;  // x re-read: L2-hot
    }
  }
}

extern "C" void kernel_launch(void* const* d_in, const int* in_sizes, int n_in,
                              void* d_out, int out_size, void* d_ws, size_t ws_size,
                              hipStream_t stream) {
  (void)in_sizes; (void)n_in; (void)out_size; (void)ws_size;
  const float* x = (const float*)d_in[0];
  const float* wqk = (const float*)d_in[1];
  const float* wv = (const float*)d_in[2];
  const float* bv = (const float*)d_in[3];
  const float* wlbr = (const float*)d_in[4];
  const float* blbr = (const float*)d_in[5];
  const float* gamma = (const float*)d_in[6];
  const float* beta = (const float*)d_in[7];
  const float* mean = (const float*)d_in[8];
  const float* var = (const float*)d_in[9];
  char* ws = (char*)d_ws;
  // ws layout
  unsigned short* qkT = (unsigned short*)ws;               // 4*4096*64*2  = 2,097,152
  unsigned short* Vf = (unsigned short*)(ws + 2097152);    // 4*1048576*2 = 8,388,608 (frag-major)
  float* nrm = (float*)(ws + 10485760);                    // 16384 f32 (ex-xT space)
  float* sd = (float*)(ws + 18874368);                     // 2,048
  unsigned short* Wcat = (unsigned short*)(ws + 18876416); // 576*256*2 = 294,912
  float* out = (float*)d_out;

  k_prep<<<dim3(577), dim3(256), 0, stream>>>(wqk, wv, wlbr, blbr, gamma, beta,
                                              mean, var, Wcat, sd);
  k_proj<<<dim3(256), dim3(640), 0, stream>>>(x, Wcat, bv, qkT, Vf, nrm);
  k_attn<<<dim3(256), dim3(512), 0, stream>>>(qkT, Vf, nrm, Wcat, sd, x, out);
}